// Round 11
// baseline (512.369 us; speedup 1.0000x reference)
//
#include <hip/hip_runtime.h>
#include <math.h>

typedef unsigned short ushort_t;
typedef __attribute__((ext_vector_type(8))) unsigned short ushortx8;
typedef __attribute__((ext_vector_type(4))) unsigned short ushortx4;
typedef __attribute__((ext_vector_type(4))) float floatx4;
typedef __attribute__((ext_vector_type(8))) short frag8;   // MFMA A/B operand (8 bf16)

__device__ __forceinline__ float bf2f(ushort_t u){
  union {unsigned int i; float f;} v; v.i = ((unsigned int)u)<<16; return v.f;
}
__device__ __forceinline__ ushort_t f2bf(float f){
  union {float f; unsigned int i;} v; v.f = f;
  unsigned int x = v.i;
  unsigned int r = x + 0x7fffu + ((x>>16)&1u);
  return (ushort_t)(r>>16);
}

__device__ __forceinline__ void gload16(const void* g, void* l){
  __builtin_amdgcn_global_load_lds(
      (const __attribute__((address_space(1))) unsigned int*)g,
      (__attribute__((address_space(3))) unsigned int*)l, 16, 0, 0);
}

// ---------------- CSR build ----------------
__global__ __launch_bounds__(256) void k_count(const int* __restrict__ col, int* __restrict__ cnt, int E){
  int e = blockIdx.x*256 + threadIdx.x;
  if (e < E) atomicAdd(&cnt[col[e]], 1);
}

__global__ __launch_bounds__(256) void k_scan1(const int* __restrict__ cnt, int* __restrict__ offs,
                                               int* __restrict__ partials, int n){
  __shared__ int buf[256];
  int tid = threadIdx.x;
  int gid = blockIdx.x*256 + tid;
  int v = (gid < n) ? cnt[gid] : 0;
  buf[tid] = v; __syncthreads();
  #pragma unroll
  for (int off=1; off<256; off<<=1){
    int t = (tid >= off) ? buf[tid-off] : 0;
    __syncthreads();
    buf[tid] += t;
    __syncthreads();
  }
  if (gid < n) offs[gid] = buf[tid] - v;
  if (tid == 255) partials[blockIdx.x] = buf[255];
}

__global__ __launch_bounds__(256) void k_scan2(int* __restrict__ partials, int nb){
  __shared__ int buf[256];
  int tid = threadIdx.x;
  int v = (tid < nb) ? partials[tid] : 0;
  buf[tid] = v; __syncthreads();
  #pragma unroll
  for (int off=1; off<256; off<<=1){
    int t = (tid >= off) ? buf[tid-off] : 0;
    __syncthreads();
    buf[tid] += t;
    __syncthreads();
  }
  partials[tid] = buf[tid] - v;
}

__global__ __launch_bounds__(256) void k_scan3(int* __restrict__ offs, const int* __restrict__ partials,
                                               int n, int E){
  int gid = blockIdx.x*256 + threadIdx.x;
  if (gid < n) offs[gid] += partials[blockIdx.x];
  if (blockIdx.x == 0 && threadIdx.x == 0) offs[n] = E;
}

__global__ __launch_bounds__(256) void k_fill(const int* __restrict__ row, const int* __restrict__ col,
                                              const int* __restrict__ offs, int* __restrict__ fill,
                                              int* __restrict__ rowS, int E){
  int e = blockIdx.x*256 + threadIdx.x;
  if (e >= E) return;
  int c = col[e];
  int pos = offs[c] + atomicAdd(&fill[c], 1);
  rowS[pos] = row[e];
}

// ---------------- weight conversions ----------------
template<int K, int NC, int CNT>
__global__ __launch_bounds__(256) void k_convT_b(const float* __restrict__ src, ushort_t* __restrict__ dst){
  int idx = blockIdx.x*256 + threadIdx.x;
  if (idx >= CNT*K*NC) return;
  int l = idx / (K*NC);
  int rem = idx - l*(K*NC);
  int k = rem / NC, n = rem - k*NC;
  dst[(size_t)l*K*NC + (size_t)n*K + k] = f2bf(src[idx]);
}

__global__ __launch_bounds__(256) void k_convT4(const float* __restrict__ s0, const float* __restrict__ s1,
                                                const float* __restrict__ s2, const float* __restrict__ s3,
                                                ushort_t* __restrict__ d0, ushort_t* __restrict__ d1,
                                                ushort_t* __restrict__ d2, ushort_t* __restrict__ d3){
  int idx = blockIdx.x*256 + threadIdx.x;
  if (idx >= 4*16384) return;
  int which = idx >> 14;
  int rem = idx & 16383;
  int k = rem >> 7, n = rem & 127;
  const float* s = which==0 ? s0 : which==1 ? s1 : which==2 ? s2 : s3;
  ushort_t*    d = which==0 ? d0 : which==1 ? d1 : which==2 ? d2 : d3;
  d[n*128 + k] = f2bf(s[rem]);
}

// ---------------- fused-kernel building blocks (TRANSPOSED mfma + 2-phase dbuf pipeline) ----------------
// mfma(b, a) computes C^T: lane (lm=lane&15, hi=lane>>4) holds
//   C[row = tileR + lm][col = tileC + hi*4 + r], r = 0..3.
//
// LDS arena SM (64 KB, ushort_t[32768]):
//   SA0 = SM[0..8192)        SA1 = SM[8192..16384)     (A-tile dbuf, [128][64])
//   SB0 = SM[16384..24576)   SB1 = SM[24576..32768)    (B-tile dbuf, [128][64])
//   LA128 = SM[0..16384)                                ([128][128] x_bf16; aliases SA0/SA1)

// stage a [128 rows][64 k] bf16 tile from row-major global (ld elems) into lds (stride 64)
__device__ __forceinline__ void stage_tile64(const ushort_t* src, int ld, int row0, int M, int kc,
                                             ushort_t* lds, int tid){
  int wid = tid>>6, lane = tid&63;
  #pragma unroll
  for (int i=0;i<4;i++){
    int chunk = wid*256 + i*64 + lane;   // 0..1023 (16B chunks)
    int r = chunk>>3, c8 = chunk&7;
    int gr = row0 + r; if (gr >= M) gr = M-1;
    gload16(src + (size_t)gr*ld + kc + c8*8, (char*)lds + (size_t)chunk*16);
  }
}

// GEMM on LDS tiles: acc(C^T frag) += LA[128xK] * LB[128xK]^T  (strides SA/SB, K = NKS*32)
template<int SA,int SB,int NKS>
__device__ __forceinline__ void ldsgemm(const ushort_t* LA, const ushort_t* LB,
                                        floatx4 (&acc)[4][4], int wr,int wc,int lm,int lk){
  #pragma unroll
  for (int ks=0; ks<NKS; ks++){
    frag8 a[4], b[4];
    #pragma unroll
    for (int mi=0;mi<4;mi++) a[mi] = *(const frag8*)&LA[(wr+mi*16+lm)*SA + ks*32 + lk];
    #pragma unroll
    for (int ni=0;ni<4;ni++) b[ni] = *(const frag8*)&LB[(wc+ni*16+lm)*SB + ks*32 + lk];
    #pragma unroll
    for (int mi=0;mi<4;mi++)
      #pragma unroll
      for (int ni=0;ni<4;ni++)
        acc[mi][ni] = __builtin_amdgcn_mfma_f32_16x16x32_bf16(b[ni], a[mi], acc[mi][ni], 0, 0, 0);
  }
}

__device__ __forceinline__ void zero_acc(floatx4 (&acc)[4][4]){
  #pragma unroll
  for (int i=0;i<4;i++)
    #pragma unroll
    for (int j=0;j<4;j++) acc[i][j] = floatx4{0.f,0.f,0.f,0.f};
}

// s_src/s_dst for one head (transposed acc: lane holds cols lr4+r of row lm)
__device__ __forceinline__ void sdst_block(const floatx4 (&acc)[4][4],
    const float* avec_s, const float* avec_d, float* s_src, float* s_dst, float* sred,
    int head, int bm, int M, int tid, int wid, int lane, int wr, int wc, int lm, int lr4){
  floatx4 avs[4], avd[4];
  #pragma unroll
  for (int ni=0;ni<4;ni++){
    avs[ni] = *(const floatx4*)&avec_s[head*128 + wc + ni*16 + lr4];
    avd[ni] = *(const floatx4*)&avec_d[head*128 + wc + ni*16 + lr4];
  }
  #pragma unroll
  for (int mi=0;mi<4;mi++){
    float vs = 0.f, vd = 0.f;
    #pragma unroll
    for (int ni=0;ni<4;ni++)
      #pragma unroll
      for (int r=0;r<4;r++){
        float v = acc[mi][ni][r];
        vs += v * avs[ni][r];
        vd += v * avd[ni][r];
      }
    vs += __shfl_xor(vs, 16); vs += __shfl_xor(vs, 32);
    vd += __shfl_xor(vd, 16); vd += __shfl_xor(vd, 32);
    if (lane < 16){                      // hi == 0
      int rl = wr + mi*16 + lm;
      sred[0*256 + (wid&1)*128 + rl] = vs;
      sred[1*256 + (wid&1)*128 + rl] = vd;
    }
  }
  __syncthreads();
  int sd = tid >> 7, rl = tid & 127;
  float v = sred[sd*256 + rl] + sred[sd*256 + 128 + rl];
  int rowg = bm + rl;
  if (rowg < M) (sd ? s_dst : s_src)[(size_t)rowg*4 + head] = v;
}

// per-head W-GEMM, double-buffered B staging. Precondition: LA128(=SM) holds x bf16,
// SB0 holds W head0 k0, all waves past a barrier after those writes.
__device__ __forceinline__ void wgemm_heads_db(ushort_t* SM,
    const ushort_t* __restrict__ WT, const float* avsv, const float* avdv,
    ushort_t* __restrict__ h, float* __restrict__ s_src, float* __restrict__ s_dst, float* sred,
    int bm, int M, int tid, int wid, int lane, int wr, int wc, int lm, int lk, int lr4){
  floatx4 acc[4][4];
  #pragma unroll
  for (int ht=0; ht<8; ht++){
    const int cur = ht&1;
    if (ht<7){
      const int nhb = (ht+1)>>1, nkph = (ht+1)&1;
      stage_tile64(WT + (size_t)nhb*16384, 128, 0, 128, nkph*64, SM + 16384 + (cur^1)*8192, tid);
    }
    if ((ht&1)==0) zero_acc(acc);
    ldsgemm<128,64,2>(SM + (ht&1)*64, SM + 16384 + cur*8192, acc, wr, wc, lm, lk);
    if (ht&1){
      const int hb = ht>>1;
      #pragma unroll
      for (int mi=0;mi<4;mi++){
        int rowg = bm + wr + mi*16 + lm;
        if (rowg < M){
          #pragma unroll
          for (int ni=0;ni<4;ni++){
            int coll = wc + ni*16 + lr4;
            ushortx4 o;
            #pragma unroll
            for (int r=0;r<4;r++) o[r] = f2bf(acc[mi][ni][r]);
            *(ushortx4*)&h[(size_t)rowg*512 + hb*128 + coll] = o;
          }
        }
      }
      sdst_block(acc, avsv, avdv, s_src, s_dst, sred, hb, bm, M, tid, wid, lane, wr, wc, lm, lr4);
    }
    __syncthreads();
  }
}

// ---------------- k_enc: conv + enc1(relu) + enc2 -> x ; + WGEMM layer0 + SDST ----------------
__global__ __launch_bounds__(256) void k_enc(
    const float* __restrict__ nodef,
    const ushort_t* __restrict__ e1T, const float* __restrict__ eb1,
    const ushort_t* __restrict__ e2T, const float* __restrict__ eb2,
    const ushort_t* __restrict__ WT, const float* __restrict__ avs, const float* __restrict__ avd,
    float* __restrict__ x, ushort_t* __restrict__ h,
    float* __restrict__ s_src, float* __restrict__ s_dst, int M)
{
  __shared__ ushort_t SM[32768];
  __shared__ float sred[512];
  const int tid = threadIdx.x, wid = tid>>6, lane = tid&63;
  const int bm = blockIdx.x*128;
  const int wr = (wid>>1)*64, wc = (wid&1)*64, lm = lane&15, lk = (lane>>4)*8, lr4 = (lane>>4)*4;
  ushort_t* SB0 = SM + 16384;
  ushort_t* SB1 = SM + 24576;

  // stage node features (f32 -> bf16) into LA128 + first e1T tile into SB0
  #pragma unroll
  for (int i=0;i<8;i++){
    int chunk = tid + 256*i;                 // 0..2047, 8 elems each
    int r = chunk>>4, c8 = chunk&15;
    int gr = bm + r; if (gr >= M) gr = M-1;
    floatx4 lo = *(const floatx4*)(nodef + (size_t)gr*128 + c8*8);
    floatx4 hi = *(const floatx4*)(nodef + (size_t)gr*128 + c8*8 + 4);
    ushortx8 v;
    #pragma unroll
    for (int j=0;j<4;j++){ v[j] = f2bf(lo[j]); v[j+4] = f2bf(hi[j]); }
    *(ushortx8*)&SM[r*128 + c8*8] = v;
  }
  stage_tile64(e1T, 128, 0, 128, 0, SB0, tid);
  __syncthreads();

  floatx4 acc[4][4]; zero_acc(acc);
  // enc1 tile0 ; prefetch enc1 tile1
  stage_tile64(e1T, 128, 0, 128, 64, SB1, tid);
  ldsgemm<128,64,2>(SM + 0, SB0, acc, wr, wc, lm, lk);
  __syncthreads();
  // enc1 tile1 ; prefetch enc2 tile0
  stage_tile64(e2T, 128, 0, 128, 0, SB0, tid);
  ldsgemm<128,64,2>(SM + 64, SB1, acc, wr, wc, lm, lk);
  __syncthreads();

  // t1 = relu(acc + eb1) -> LA128 ; prefetch enc2 tile1
  stage_tile64(e2T, 128, 0, 128, 64, SB1, tid);
  #pragma unroll
  for (int mi=0;mi<4;mi++){
    int rl = wr + mi*16 + lm;
    #pragma unroll
    for (int ni=0;ni<4;ni++){
      int coll = wc + ni*16 + lr4;
      floatx4 b4 = *(const floatx4*)&eb1[coll];
      ushortx4 o;
      #pragma unroll
      for (int r=0;r<4;r++){
        float v = acc[mi][ni][r] + b4[r];
        v = v > 0.f ? v : 0.f;
        o[r] = f2bf(v);
      }
      *(ushortx4*)&SM[rl*128 + coll] = o;
    }
  }
  __syncthreads();

  zero_acc(acc);
  // enc2 tile0
  ldsgemm<128,64,2>(SM + 0, SB0, acc, wr, wc, lm, lk);
  __syncthreads();
  // enc2 tile1 ; prefetch W head0 k0
  stage_tile64(WT, 128, 0, 128, 0, SB0, tid);
  ldsgemm<128,64,2>(SM + 64, SB1, acc, wr, wc, lm, lk);
  __syncthreads();

  // x = acc + eb2 -> global f32 (16B) + LA128 bf16 (8B)
  #pragma unroll
  for (int mi=0;mi<4;mi++){
    int rl = wr + mi*16 + lm;
    int rowg = bm + rl;
    #pragma unroll
    for (int ni=0;ni<4;ni++){
      int coll = wc + ni*16 + lr4;
      floatx4 b4 = *(const floatx4*)&eb2[coll];
      floatx4 v;
      #pragma unroll
      for (int r=0;r<4;r++) v[r] = acc[mi][ni][r] + b4[r];
      if (rowg < M) *(floatx4*)&x[(size_t)rowg*128 + coll] = v;
      ushortx4 o;
      #pragma unroll
      for (int r=0;r<4;r++) o[r] = f2bf(v[r]);
      *(ushortx4*)&SM[rl*128 + coll] = o;
    }
  }
  __syncthreads();

  wgemm_heads_db(SM, WT, avs, avd, h, s_src, s_dst, sred,
                 bm, M, tid, wid, lane, wr, wc, lm, lk, lr4);
}

// ---------------- k_mid: out-proj + bias + resid -> x ; + next WGEMM + SDST ----------------
__global__ __launch_bounds__(256) void k_mid(
    const ushort_t* __restrict__ msg, const ushort_t* __restrict__ OT, const float* __restrict__ ob,
    const ushort_t* __restrict__ WT, const float* __restrict__ avs, const float* __restrict__ avd,
    float* __restrict__ x, ushort_t* __restrict__ h,
    float* __restrict__ s_src, float* __restrict__ s_dst, int M)
{
  __shared__ ushort_t SM[32768];
  __shared__ float sred[512];
  const int tid = threadIdx.x, wid = tid>>6, lane = tid&63;
  const int bm = blockIdx.x*128;
  const int wr = (wid>>1)*64, wc = (wid&1)*64, lm = lane&15, lk = (lane>>4)*8, lr4 = (lane>>4)*4;

  floatx4 acc[4][4]; zero_acc(acc);
  // out-proj: 8 K-tiles, double-buffered A(msg) and B(OT)
  stage_tile64(msg, 512, bm, M, 0, SM, tid);
  stage_tile64(OT,  512, 0, 128, 0, SM + 16384, tid);
  __syncthreads();
  #pragma unroll
  for (int t=0; t<8; t++){
    const int cur = t&1;
    if (t<7){
      stage_tile64(msg, 512, bm, M, (t+1)*64, SM + (cur^1)*8192, tid);
      stage_tile64(OT,  512, 0, 128, (t+1)*64, SM + 16384 + (cur^1)*8192, tid);
    }
    ldsgemm<64,64,2>(SM + cur*8192, SM + 16384 + cur*8192, acc, wr, wc, lm, lk);
    __syncthreads();
  }

  // x_new = acc + ob + x_old -> global f32 + LA128 bf16 ; prefetch W head0 k0
  stage_tile64(WT, 128, 0, 128, 0, SM + 16384, tid);
  #pragma unroll
  for (int mi=0;mi<4;mi++){
    int rl = wr + mi*16 + lm;
    int rowg = bm + rl;
    #pragma unroll
    for (int ni=0;ni<4;ni++){
      int coll = wc + ni*16 + lr4;
      floatx4 b4 = *(const floatx4*)&ob[coll];
      floatx4 v;
      #pragma unroll
      for (int r=0;r<4;r++) v[r] = acc[mi][ni][r] + b4[r];
      if (rowg < M){
        floatx4 xo = *(const floatx4*)&x[(size_t)rowg*128 + coll];
        #pragma unroll
        for (int r=0;r<4;r++) v[r] += xo[r];
        *(floatx4*)&x[(size_t)rowg*128 + coll] = v;
      }
      ushortx4 o;
      #pragma unroll
      for (int r=0;r<4;r++) o[r] = f2bf(v[r]);
      *(ushortx4*)&SM[rl*128 + coll] = o;
    }
  }
  __syncthreads();

  wgemm_heads_db(SM, WT, avs, avd, h, s_src, s_dst, sred,
                 bm, M, tid, wid, lane, wr, wc, lm, lk, lr4);
}

// ---------------- k_tail: out-proj3 + resid -> MLP1(relu) -> MLP2 -> d_out + colsum ----------------
__global__ __launch_bounds__(256) void k_tail(
    const ushort_t* __restrict__ msg, const ushort_t* __restrict__ OT, const float* __restrict__ ob,
    const ushort_t* __restrict__ m1T, const float* __restrict__ mb1,
    const ushort_t* __restrict__ m2T, const float* __restrict__ mb2,
    const float* __restrict__ x, float* __restrict__ out, float* __restrict__ cpart, int M)
{
  __shared__ ushort_t SM[32768];
  __shared__ float sredc[256];
  const int tid = threadIdx.x, wid = tid>>6, lane = tid&63;
  const int bm = blockIdx.x*128;
  const int wr = (wid>>1)*64, wc = (wid&1)*64, lm = lane&15, lk = (lane>>4)*8, lr4 = (lane>>4)*4;
  ushort_t* SB0 = SM + 16384;
  ushort_t* SB1 = SM + 24576;

  floatx4 acc[4][4]; zero_acc(acc);
  stage_tile64(msg, 512, bm, M, 0, SM, tid);
  stage_tile64(OT,  512, 0, 128, 0, SB0, tid);
  __syncthreads();
  #pragma unroll
  for (int t=0; t<8; t++){
    const int cur = t&1;
    if (t<7){
      stage_tile64(msg, 512, bm, M, (t+1)*64, SM + (cur^1)*8192, tid);
      stage_tile64(OT,  512, 0, 128, (t+1)*64, SM + 16384 + (cur^1)*8192, tid);
    }
    ldsgemm<64,64,2>(SM + cur*8192, SM + 16384 + cur*8192, acc, wr, wc, lm, lk);
    __syncthreads();
  }

  // x3 = acc + ob + x_old -> LA128 bf16 ; prefetch m1T tile0
  stage_tile64(m1T, 128, 0, 128, 0, SB0, tid);
  #pragma unroll
  for (int mi=0;mi<4;mi++){
    int rl = wr + mi*16 + lm;
    int rowg = bm + rl;
    #pragma unroll
    for (int ni=0;ni<4;ni++){
      int coll = wc + ni*16 + lr4;
      floatx4 b4 = *(const floatx4*)&ob[coll];
      floatx4 v;
      #pragma unroll
      for (int r=0;r<4;r++) v[r] = acc[mi][ni][r] + b4[r];
      if (rowg < M){
        floatx4 xo = *(const floatx4*)&x[(size_t)rowg*128 + coll];
        #pragma unroll
        for (int r=0;r<4;r++) v[r] += xo[r];
      }
      ushortx4 o;
      #pragma unroll
      for (int r=0;r<4;r++) o[r] = f2bf(v[r]);
      *(ushortx4*)&SM[rl*128 + coll] = o;
    }
  }
  __syncthreads();

  zero_acc(acc);
  // mlp1 tile0 ; prefetch m1T tile1
  stage_tile64(m1T, 128, 0, 128, 64, SB1, tid);
  ldsgemm<128,64,2>(SM + 0, SB0, acc, wr, wc, lm, lk);
  __syncthreads();
  // mlp1 tile1 ; prefetch m2T tile0
  stage_tile64(m2T, 128, 0, 128, 0, SB0, tid);
  ldsgemm<128,64,2>(SM + 64, SB1, acc, wr, wc, lm, lk);
  __syncthreads();

  // t = relu(acc + mb1) -> LA128 ; prefetch m2T tile1
  stage_tile64(m2T, 128, 0, 128, 64, SB1, tid);
  #pragma unroll
  for (int mi=0;mi<4;mi++){
    int rl = wr + mi*16 + lm;
    #pragma unroll
    for (int ni=0;ni<4;ni++){
      int coll = wc + ni*16 + lr4;
      floatx4 b4 = *(const floatx4*)&mb1[coll];
      ushortx4 o;
      #pragma unroll
      for (int r=0;r<4;r++){
        float v = acc[mi][ni][r] + b4[r];
        v = v > 0.f ? v : 0.f;
        o[r] = f2bf(v);
      }
      *(ushortx4*)&SM[rl*128 + coll] = o;
    }
  }
  __syncthreads();

  zero_acc(acc);
  ldsgemm<128,64,2>(SM + 0, SB0, acc, wr, wc, lm, lk);
  __syncthreads();
  ldsgemm<128,64,2>(SM + 64, SB1, acc, wr, wc, lm, lk);

  float csum[4][4];
  #pragma unroll
  for (int i=0;i<4;i++)
    #pragma unroll
    for (int r=0;r<4;r++) csum[i][r] = 0.f;
  #pragma unroll
  for (int mi=0;mi<4;mi++){
    int rowg = bm + wr + mi*16 + lm;
    #pragma unroll
    for (int ni=0;ni<4;ni++){
      int coll = wc + ni*16 + lr4;
      floatx4 b4 = *(const floatx4*)&mb2[coll];
      floatx4 v;
      #pragma unroll
      for (int r=0;r<4;r++) v[r] = acc[mi][ni][r] + b4[r];
      if (rowg < M){
        *(floatx4*)&out[(size_t)rowg*128 + coll] = v;
        #pragma unroll
        for (int r=0;r<4;r++) csum[ni][r] += v[r];
      }
    }
  }
  __syncthreads();
  #pragma unroll
  for (int ni=0;ni<4;ni++)
    #pragma unroll
    for (int r=0;r<4;r++){
      float cs = csum[ni][r];
      cs += __shfl_xor(cs, 1);
      cs += __shfl_xor(cs, 2);
      cs += __shfl_xor(cs, 4);
      cs += __shfl_xor(cs, 8);
      if (lm == 0) sredc[(wid>>1)*128 + wc + ni*16 + lr4 + r] = cs;
    }
  __syncthreads();
  if (tid < 128) cpart[(size_t)blockIdx.x*128 + tid] = sredc[tid] + sredc[128 + tid];
}

// ---------------- fused attention gather (round-5 structure) ----------------
__global__ __launch_bounds__(256) void k_gather(const ushort_t* __restrict__ h,
    const float* __restrict__ s_src, const float* __restrict__ s_dst,
    const int* __restrict__ offs, const int* __restrict__ rowS,
    ushort_t* __restrict__ msg, int N)
{
  int wid = threadIdx.x >> 6, lane = threadIdx.x & 63;
  int n = blockIdx.x*4 + wid;
  if (n >= N) return;
  int beg = offs[n], end = offs[n+1];
  const int sub  = lane & 15;
  const int head = lane >> 4;
  const float sdv = s_dst[(size_t)n*4 + head];
  const int c0 = lane*8;

  float acc[8];
  #pragma unroll
  for (int k=0;k<8;k++) acc[k] = 0.f;
  float dsum = 0.f;

  for (int chunk = beg; chunk < end; chunk += 16){
    int m = end - chunk; if (m > 16) m = 16;
    int q = chunk + (sub < m ? sub : m-1);
    int r_p = rowS[q];
    float ss = s_src[(size_t)r_p*4 + head];
    float e = ss + sdv;
    e = e > 0.f ? e : 0.2f*e;
    float w = __expf(e);
    if (sub >= m) w = 0.f;
    dsum += w;

    int j = 0;
    for (; j+1 < m; j += 2){
      int r0 = __shfl(r_p, j);
      int r1 = __shfl(r_p, j+1);
      float w0 = __shfl(w, head*16 + j);
      float w1 = __shfl(w, head*16 + j+1);
      ushortx8 h0 = *(const ushortx8*)(h + (size_t)r0*512 + c0);
      ushortx8 h1 = *(const ushortx8*)(h + (size_t)r1*512 + c0);
      #pragma unroll
      for (int k=0;k<8;k++) acc[k] += w0 * bf2f(h0[k]);
      #pragma unroll
      for (int k=0;k<8;k++) acc[k] += w1 * bf2f(h1[k]);
    }
    if (j < m){
      int r0 = __shfl(r_p, j);
      float w0 = __shfl(w, head*16 + j);
      ushortx8 h0 = *(const ushortx8*)(h + (size_t)r0*512 + c0);
      #pragma unroll
      for (int k=0;k<8;k++) acc[k] += w0 * bf2f(h0[k]);
    }
  }

  float d = dsum;
  #pragma unroll
  for (int mask=1; mask<16; mask<<=1) d += __shfl_xor(d, mask);
  float invd = 1.0f / (d + 1e-8f);

  ushortx8 o;
  #pragma unroll
  for (int k=0;k<8;k++) o[k] = f2bf(acc[k]*invd);
  __builtin_nontemporal_store(o, (ushortx8*)(msg + (size_t)n*512 + c0));
}

// ---------------- reduce per-block column partials -> mean ----------------
__global__ __launch_bounds__(256) void k_csum2(const float* __restrict__ part, float* __restrict__ out,
                                               int nb, int N){
  __shared__ float buf[256];
  int c = threadIdx.x & 127, half = threadIdx.x >> 7;
  float s = 0.f;
  for (int b = half; b < nb; b += 2) s += part[(size_t)b*128 + c];
  buf[threadIdx.x] = s; __syncthreads();
  if (threadIdx.x < 128) out[c] = (buf[c] + buf[128 + c]) / (float)N;
}

extern "C" void kernel_launch(void* const* d_in, const int* in_sizes, int n_in,
                              void* d_out, int out_size, void* d_ws, size_t ws_size,
                              hipStream_t stream)
{
  const int N = in_sizes[0] / 128;
  const int E = in_sizes[1] / 2;

  const float* nodef  = (const float*)d_in[0];
  const int*   row    = (const int*)d_in[1];
  const int*   col    = row + E;
  const float* enc_w1 = (const float*)d_in[2];
  const float* enc_b1 = (const float*)d_in[3];
  const float* enc_w2 = (const float*)d_in[4];
  const float* enc_b2 = (const float*)d_in[5];
  const float* gat_W  = (const float*)d_in[6];
  const float* a_src  = (const float*)d_in[7];
  const float* a_dst  = (const float*)d_in[8];
  const float* out_w  = (const float*)d_in[9];
  const float* out_b  = (const float*)d_in[10];
  const float* w1     = (const float*)d_in[11];
  const float* b1     = (const float*)d_in[12];
  const float* w2     = (const float*)d_in[13];
  const float* b2     = (const float*)d_in[14];

  char* p = (char*)d_ws;
  auto alloc = [&](size_t bytes)->char*{
    char* r = p; p += (bytes + 255) & ~(size_t)255; return r;
  };
  float*    x     = (float*)   alloc((size_t)N*128*4);
  ushort_t* msg   = (ushort_t*)alloc((size_t)N*512*2);
  ushort_t* h     = (ushort_t*)alloc((size_t)N*512*2);
  float*    s_src = (float*)   alloc((size_t)N*4*4);
  float*    s_dst = (float*)   alloc((size_t)N*4*4);
  int*      offs  = (int*)     alloc(((size_t)N+1)*4);
  int*      rowS  = (int*)     alloc((size_t)E*4);
  int*      cnt   = (int*)     alloc((size_t)N*4);
  int*      fill  = (int*)     alloc((size_t)N*4);
  int*      parts = (int*)     alloc(1024);
  float*    cpart = (float*)   alloc((size_t)((N+127)/128)*128*4);
  ushort_t* wt_e1 = (ushort_t*)alloc(16384*2);
  ushort_t* wt_e2 = (ushort_t*)alloc(16384*2);
  ushort_t* wt_W  = (ushort_t*)alloc((size_t)3*65536*2);
  ushort_t* wt_o  = (ushort_t*)alloc((size_t)3*65536*2);
  ushort_t* wt_m1 = (ushort_t*)alloc(16384*2);
  ushort_t* wt_m2 = (ushort_t*)alloc(16384*2);

  hipMemsetAsync(cnt, 0, (size_t)N*4, stream);
  hipMemsetAsync(fill, 0, (size_t)N*4, stream);

  const int gE = (E + 255)/256;
  const int gN = (N + 255)/256;
  const int gW = (N + 3)/4;
  const int gy = (N + 127)/128;
  dim3 blk(256);

  // CSR by destination
  k_count<<<gE, blk, 0, stream>>>(col, cnt, E);
  k_scan1<<<gN, blk, 0, stream>>>(cnt, offs, parts, N);
  k_scan2<<<1,  blk, 0, stream>>>(parts, gN);
  k_scan3<<<gN, blk, 0, stream>>>(offs, parts, N, E);
  k_fill <<<gE, blk, 0, stream>>>(row, col, offs, fill, rowS, E);

  // weight conversion (bf16, transposed to [NC,K])
  k_convT4<<<(4*16384+255)/256, blk, 0, stream>>>(enc_w1, enc_w2, w1, w2, wt_e1, wt_e2, wt_m1, wt_m2);
  k_convT_b<128,512,3><<<(3*65536+255)/256, blk, 0, stream>>>(gat_W, wt_W);
  k_convT_b<512,128,3><<<(3*65536+255)/256, blk, 0, stream>>>(out_w, wt_o);

  // encoder + layer-0 W-GEMM + SDST
  k_enc<<<gy, blk, 0, stream>>>(nodef, wt_e1, enc_b1, wt_e2, enc_b2,
                                wt_W, a_src, a_dst, x, h, s_src, s_dst, N);

  for (int l = 0; l < 3; l++){
    k_gather<<<gW, blk, 0, stream>>>(h, s_src, s_dst, offs, rowS, msg, N);
    if (l < 2){
      k_mid<<<gy, blk, 0, stream>>>(msg, wt_o + (size_t)l*65536, out_b + (size_t)l*128,
                                    wt_W + (size_t)(l+1)*65536,
                                    a_src + (size_t)(l+1)*512, a_dst + (size_t)(l+1)*512,
                                    x, h, s_src, s_dst, N);
    } else {
      k_tail<<<gy, blk, 0, stream>>>(msg, wt_o + (size_t)2*65536, out_b + (size_t)2*128,
                                     wt_m1, b1, wt_m2, b2,
                                     x, (float*)d_out, cpart, N);
    }
  }
  k_csum2<<<1, blk, 0, stream>>>(cpart, (float*)d_out + (size_t)N*128, gy, N);
}